// Round 1
// baseline (820.695 us; speedup 1.0000x reference)
//
#include <hip/hip_runtime.h>

#define NN 16
#define SS 16384
#define VV 256
#define TT ((long)NN * SS)   // 262144 tokens
#define NC 47                // total codes
#define SUT_STRIDE 48        // padded row for suT [v][c]
#define TOKB 512             // tokens per fused block (2 per thread)
#define XT_LD 516            // padded LDS row stride (516%32=4 -> conflict-free stores)

static constexpr int CB_SIZES_H[10] = {3, 5, 5, 5, 5, 3, 7, 8, 3, 3};
static constexpr int CB_OFF_H[10]   = {0, 3, 8, 13, 18, 23, 26, 33, 41, 44};

typedef float v4f __attribute__((ext_vector_type(4)));

// ---------------------------------------------------------------------------
// Precompute: suT[v][gc] = -2*W1_g^T e_c ; proj[gc][v] = W2[:,i*10+g]·e ;
// biasv[gc] = e·e - 2 b1_g·e
// ---------------------------------------------------------------------------
__global__ __launch_bounds__(256) void vq_pre(
    const float* __restrict__ W1, const float* __restrict__ b1,
    const float* __restrict__ W2,
    const float* __restrict__ cb0, const float* __restrict__ cb1,
    const float* __restrict__ cb2, const float* __restrict__ cb3,
    const float* __restrict__ cb4, const float* __restrict__ cb5,
    const float* __restrict__ cb6, const float* __restrict__ cb7,
    const float* __restrict__ cb8, const float* __restrict__ cb9,
    float* __restrict__ suT, float* __restrict__ biasv,
    float* __restrict__ proj)
{
    const float* cbs[10] = {cb0, cb1, cb2, cb3, cb4, cb5, cb6, cb7, cb8, cb9};
    const int gc = blockIdx.x;           // 0..46
    int g = 0;
    #pragma unroll
    for (int gg = 1; gg < 10; gg++) if (gc >= CB_OFF_H[gg]) g = gg;
    const int c = gc - CB_OFF_H[g];
    const float* e = cbs[g] + c * 16;

    const int v = threadIdx.x;           // 0..255
    float su = 0.f, pj = 0.f;
    #pragma unroll
    for (int i = 0; i < 16; i++)
        su = fmaf(W1[(long)(16 * g + i) * VV + v], e[i], su);
    suT[v * SUT_STRIDE + gc] = -2.f * su;
    #pragma unroll
    for (int i = 0; i < 16; i++)
        pj = fmaf(e[i], W2[(long)v * 160 + i * 10 + g], pj);
    proj[gc * VV + v] = pj;

    if (v == 0) {
        float b = 0.f;
        #pragma unroll
        for (int i = 0; i < 16; i++)
            b += e[i] * (e[i] - 2.f * b1[16 * g + i]);
        biasv[gc] = b;
    }
}

// ---------------------------------------------------------------------------
// Fused kernel: phase 1 = scores + argmin (2 tokens/thread, xv hoisted to
// VGPRs so the FMA stream only waits on SMEM srow loads); phase 2 = output
// streaming with proj in the same LDS buffer, pk kept in registers.
// ---------------------------------------------------------------------------
static __device__ __forceinline__ unsigned argmin_pack(const float* acc) {
    unsigned p = 0;
    #pragma unroll
    for (int g = 0; g < 10; g++) {
        const int off = CB_OFF_H[g];
        const int k = CB_SIZES_H[g];
        float best = acc[off];
        int bi = 0;
        #pragma unroll
        for (int c = 1; c < 8; c++) {
            if (c < k) {
                const float vv = acc[off + c];
                if (vv < best) { best = vv; bi = c; }  // strict <: np first-min
            }
        }
        p |= (unsigned)bi << (3 * g);
    }
    return p;
}

__global__ __launch_bounds__(256, 2) void vq_fused(
    const float* __restrict__ x, const float* __restrict__ suT,
    const float* __restrict__ biasv, const float* __restrict__ proj,
    const float* __restrict__ b2,
    float* __restrict__ out0, float* __restrict__ out1,
    float* __restrict__ out2)
{
    __shared__ __align__(16) char smem[NC * 64 * 16];   // 48128 B
    float* xt = (float*)smem;                           // phase1: [16][XT_LD]
    v4f*  pl  = (v4f*)smem;                             // phase2: [NC][64]

    const int tid = threadIdx.x;
    const long t0 = (long)blockIdx.x * TOKB;

    float acc0[NC], acc1[NC];
    #pragma unroll
    for (int c = 0; c < NC; c++) { const float b = biasv[c]; acc0[c] = b; acc1[c] = b; }

    const int q  = tid & 3;      // which float4 of the 16-v chunk
    const int t4 = tid >> 2;     // 0..63 base token within tile

    #pragma unroll 1
    for (int v0 = 0; v0 < VV; v0 += 16) {
        __syncthreads();   // previous chunk's reads done before overwrite
        #pragma unroll
        for (int jj = 0; jj < 8; jj++) {
            const int tt = t4 + 64 * jj;
            const float4 qv = *(const float4*)(x + (t0 + tt) * VV + v0 + 4 * q);
            xt[(4 * q + 0) * XT_LD + tt] = qv.x;
            xt[(4 * q + 1) * XT_LD + tt] = qv.y;
            xt[(4 * q + 2) * XT_LD + tt] = qv.z;
            xt[(4 * q + 3) * XT_LD + tt] = qv.w;
        }
        __syncthreads();

        // hoist ALL LDS reads of this chunk into VGPRs so the FMA region
        // below has only SMEM (srow) lgkm waits to schedule around
        float xa[16], xb[16];
        #pragma unroll
        for (int v = 0; v < 16; v++) {
            xa[v] = xt[v * XT_LD + tid];
            xb[v] = xt[v * XT_LD + tid + 256];
        }
        #pragma unroll
        for (int v = 0; v < 16; v++) {
            const float* srow = suT + (long)(v0 + v) * SUT_STRIDE;  // wave-uniform
            const float xva = xa[v], xvb = xb[v];
            #pragma unroll
            for (int c = 0; c < NC; c++) {
                const float s = srow[c];
                acc0[c] = fmaf(xva, s, acc0[c]);
                acc1[c] = fmaf(xvb, s, acc1[c]);
            }
        }
    }

    const unsigned p0 = argmin_pack(acc0);   // token t0 + tid
    const unsigned p1 = argmin_pack(acc1);   // token t0 + 256 + tid

    // ---- phase 2: overwrite LDS with proj, stream output ----
    __syncthreads();                          // all waves done with xt
    for (int i = tid; i < NC * 64; i += 256)
        pl[i] = ((const v4f*)proj)[i];
    __syncthreads();

    const int lane = tid & 63;
    const int w    = tid >> 6;
    const v4f b2v = ((const v4f*)b2)[lane];
    const long tb0 = t0 + (long)w * 64;

    #pragma unroll 1
    for (int half = 0; half < 2; half++) {
        const unsigned pkme = half ? p1 : p0;
        const long tbase = tb0 + half * 256;
        #pragma unroll 1
        for (int tok = 0; tok < 64; tok++) {
            const unsigned pkt = (unsigned)__shfl((int)pkme, tok);
            v4f o = b2v;
            #pragma unroll
            for (int g = 0; g < 10; g++) {
                const int cc = CB_OFF_H[g] + (int)((pkt >> (3 * g)) & 7u);
                o += pl[cc * 64 + lane];
            }
            const long t = tbase + tok;
            const v4f xv = ((const v4f*)(x + t * VV))[lane];
            v4f s = (o - xv) + xv;   // match reference rounding for out0
            __builtin_nontemporal_store(s, (v4f*)(out0 + t * VV) + lane);

            const v4f d = xv - o;
            float pr = d.x * d.x + d.y * d.y + d.z * d.z + d.w * d.w;
            #pragma unroll
            for (int off = 32; off > 0; off >>= 1)
                pr += __shfl_xor(pr, off);
            if (lane == 0)  out1[t] = pr;
            if (lane == 32) out2[t] = pr;
        }
    }
}

// ---------------------------------------------------------------------------
extern "C" void kernel_launch(void* const* d_in, const int* in_sizes, int n_in,
                              void* d_out, int out_size, void* d_ws, size_t ws_size,
                              hipStream_t stream) {
    const float* x0 = (const float*)d_in[0];
    const float* W1 = (const float*)d_in[1];
    const float* b1 = (const float*)d_in[2];
    const float* W2 = (const float*)d_in[3];
    const float* b2 = (const float*)d_in[4];
    const float* cb[10];
    for (int i = 0; i < 10; i++) cb[i] = (const float*)d_in[5 + i];

    float* ws    = (float*)d_ws;
    float* suT   = ws;                        // 256*48 = 12288 floats
    float* biasv = ws + 12288;                // 48 floats
    float* proj  = ws + 12288 + 48;           // 47*256 = 12032 floats

    float* out0 = (float*)d_out;
    float* out1 = out0 + (long)NN * SS * VV;  // 67108864
    float* out2 = out1 + (long)NN * SS;       // +262144

    vq_pre<<<NC, 256, 0, stream>>>(W1, b1, W2,
        cb[0], cb[1], cb[2], cb[3], cb[4], cb[5], cb[6], cb[7], cb[8], cb[9],
        suT, biasv, proj);

    vq_fused<<<(int)(TT / TOKB), 256, 0, stream>>>(
        x0, suT, biasv, proj, b2, out0, out1, out2);
}

// Round 2
// 556.187 us; speedup vs baseline: 1.4756x; 1.4756x over previous
//
#include <hip/hip_runtime.h>

#define NN 16
#define SS 16384
#define VV 256
#define TT ((long)NN * SS)   // 262144 tokens
#define NC 47                // total codes (padded to 48 for MFMA)

static constexpr int CB_SIZES_H[10] = {3, 5, 5, 5, 5, 3, 7, 8, 3, 3};
static constexpr int CB_OFF_H[10]   = {0, 3, 8, 13, 18, 23, 26, 33, 41, 44};

typedef float v4f    __attribute__((ext_vector_type(4)));
typedef float f32x4  __attribute__((ext_vector_type(4)));
typedef short short8 __attribute__((ext_vector_type(8)));
typedef unsigned uint4e __attribute__((ext_vector_type(4)));

// ---------------------------------------------------------------------------
// Precompute. su[k][n] = -2 * (W1_g^T e_c)[k]  (k=0..255, n=gc=0..46), split
// into bf16 hi/lo and written in MFMA B-fragment order:
//   frag f = ks*3 + nt  (ks = k>>5, nt = n>>4)
//   lane  = ((k&31)>>3)*16 + (n&15),  j = k&7
//   hi at bfrag[f*512 + lane*8 + j], lo at bfrag[12288 + same]
// Column n=47 (pad) is zero-filled by block 47.
// Also biasv[gc] = e.e - 2 b1_g.e and proj[gc][v] (for vq_out), as before.
// ---------------------------------------------------------------------------
__global__ __launch_bounds__(256) void vq_pre(
    const float* __restrict__ W1, const float* __restrict__ b1,
    const float* __restrict__ W2,
    const float* __restrict__ cb0, const float* __restrict__ cb1,
    const float* __restrict__ cb2, const float* __restrict__ cb3,
    const float* __restrict__ cb4, const float* __restrict__ cb5,
    const float* __restrict__ cb6, const float* __restrict__ cb7,
    const float* __restrict__ cb8, const float* __restrict__ cb9,
    unsigned short* __restrict__ bfrag, float* __restrict__ biasv,
    float* __restrict__ proj)
{
    const int gc = blockIdx.x;           // 0..47 (47 = zero pad column)
    const int v  = threadIdx.x;          // 0..255 = k
    const int ks = v >> 5, kl = v & 31, h = kl >> 3, j = kl & 7;

    if (gc >= NC) {                      // pad column: zeros
        const int idx = (ks * 3 + 2) * 512 + (h * 16 + 15) * 8 + j;
        bfrag[idx] = 0;
        bfrag[12288 + idx] = 0;
        return;
    }

    const float* cbs[10] = {cb0, cb1, cb2, cb3, cb4, cb5, cb6, cb7, cb8, cb9};
    int g = 0;
    #pragma unroll
    for (int gg = 1; gg < 10; gg++) if (gc >= CB_OFF_H[gg]) g = gg;
    const int c = gc - CB_OFF_H[g];
    const float* e = cbs[g] + c * 16;

    float su = 0.f, pj = 0.f;
    #pragma unroll
    for (int i = 0; i < 16; i++)
        su = fmaf(W1[(long)(16 * g + i) * VV + v], e[i], su);
    const float s2 = -2.f * su;

    // split s2 = hi + lo (hi = truncated bf16, lo = RNE bf16 of residual)
    const unsigned u = __builtin_bit_cast(unsigned, s2);
    const float r = s2 - __builtin_bit_cast(float, u & 0xFFFF0000u);
    unsigned t = __builtin_bit_cast(unsigned, r);
    t += 0x7FFFu + ((t >> 16) & 1u);
    const int idx = (ks * 3 + (gc >> 4)) * 512 + (h * 16 + (gc & 15)) * 8 + j;
    bfrag[idx]         = (unsigned short)(u >> 16);
    bfrag[12288 + idx] = (unsigned short)(t >> 16);

    #pragma unroll
    for (int i = 0; i < 16; i++)
        pj = fmaf(e[i], W2[(long)v * 160 + i * 10 + g], pj);
    proj[gc * VV + v] = pj;

    if (v == 0) {
        float b = 0.f;
        #pragma unroll
        for (int i = 0; i < 16; i++)
            b += e[i] * (e[i] - 2.f * b1[16 * g + i]);
        biasv[gc] = b;
    }
}

// ---------------------------------------------------------------------------
// fp32 -> bf16 hi/lo split of 8 consecutive elements, packed for MFMA A frag
// ---------------------------------------------------------------------------
static __device__ __forceinline__ void cvt_hi_lo(
    const float4 f0, const float4 f1, short8& ah, short8& al)
{
    const float f[8] = {f0.x, f0.y, f0.z, f0.w, f1.x, f1.y, f1.z, f1.w};
    uint4e H, L;
    #pragma unroll
    for (int p = 0; p < 4; p++) {
        const unsigned u0 = __builtin_bit_cast(unsigned, f[2 * p]);
        const unsigned u1 = __builtin_bit_cast(unsigned, f[2 * p + 1]);
        H[p] = (u0 >> 16) | (u1 & 0xFFFF0000u);
        const float r0 = f[2 * p]     - __builtin_bit_cast(float, u0 & 0xFFFF0000u);
        const float r1 = f[2 * p + 1] - __builtin_bit_cast(float, u1 & 0xFFFF0000u);
        unsigned t0 = __builtin_bit_cast(unsigned, r0);
        unsigned t1 = __builtin_bit_cast(unsigned, r1);
        t0 += 0x7FFFu + ((t0 >> 16) & 1u);
        t1 += 0x7FFFu + ((t1 >> 16) & 1u);
        L[p] = (t0 >> 16) | (t1 & 0xFFFF0000u);
    }
    ah = __builtin_bit_cast(short8, H);
    al = __builtin_bit_cast(short8, L);
}

static __device__ __forceinline__ unsigned argmin_pack(const float* acc) {
    unsigned p = 0;
    #pragma unroll
    for (int g = 0; g < 10; g++) {
        const int off = CB_OFF_H[g];
        const int k = CB_SIZES_H[g];
        float best = acc[off];
        int bi = 0;
        #pragma unroll
        for (int c = 1; c < 8; c++) {
            if (c < k) {
                const float vv = acc[off + c];
                if (vv < best) { best = vv; bi = c; }  // strict <: np first-min
            }
        }
        p |= (unsigned)bi << (3 * g);
    }
    return p;
}

// ---------------------------------------------------------------------------
// Kernel A: scores via split-bf16 MFMA. Wave = 64 tokens (4 m-tiles of 16),
// 48 codes (3 n-tiles), K=256 (8 k-steps). score = Ahi*Bhi + Ahi*Blo + Alo*Bhi
// accumulated in fp32; bias added at scan time. C frags dumped to LDS
// (stride 49 -> conflict-free scan reads), then per-lane sequential argmin
// identical to the verified round-0 semantics.
// ---------------------------------------------------------------------------
__global__ __launch_bounds__(256) void vq_score_mfma(
    const float* __restrict__ x, const unsigned short* __restrict__ bfrag,
    const float* __restrict__ biasv, unsigned* __restrict__ pk)
{
    __shared__ float sc[4][64][49];      // 50176 B, per-wave private slabs
    const int tid  = threadIdx.x;
    const int w    = tid >> 6;
    const int lane = tid & 63;
    const int h    = lane >> 4;          // A: k-group ; C: row-group
    const int nl   = lane & 15;          // A: row     ; B/C: col
    const long t0  = (long)blockIdx.x * 256 + (long)w * 64;

    f32x4 acc[4][3];
    #pragma unroll
    for (int m = 0; m < 4; m++)
        #pragma unroll
        for (int nt = 0; nt < 3; nt++)
            acc[m][nt] = (f32x4){0.f, 0.f, 0.f, 0.f};

    const float* xbase[4];
    #pragma unroll
    for (int m = 0; m < 4; m++)
        xbase[m] = x + (t0 + m * 16 + nl) * VV + h * 8;

    const unsigned short* bh_ptr = bfrag + lane * 8;
    const unsigned short* bl_ptr = bfrag + 12288 + lane * 8;

    #pragma unroll 1
    for (int ks = 0; ks < 8; ks++) {
        short8 bh[3], bl[3];
        #pragma unroll
        for (int nt = 0; nt < 3; nt++) {
            bh[nt] = *(const short8*)(bh_ptr + (ks * 3 + nt) * 512);
            bl[nt] = *(const short8*)(bl_ptr + (ks * 3 + nt) * 512);
        }
        #pragma unroll
        for (int m = 0; m < 4; m++) {
            const float4 f0 = *(const float4*)(xbase[m] + ks * 32);
            const float4 f1 = *(const float4*)(xbase[m] + ks * 32 + 4);
            short8 ah, al;
            cvt_hi_lo(f0, f1, ah, al);
            #pragma unroll
            for (int nt = 0; nt < 3; nt++) {
                acc[m][nt] = __builtin_amdgcn_mfma_f32_16x16x32_bf16(ah, bh[nt], acc[m][nt], 0, 0, 0);
                acc[m][nt] = __builtin_amdgcn_mfma_f32_16x16x32_bf16(ah, bl[nt], acc[m][nt], 0, 0, 0);
                acc[m][nt] = __builtin_amdgcn_mfma_f32_16x16x32_bf16(al, bh[nt], acc[m][nt], 0, 0, 0);
            }
        }
    }

    // C layout: col = lane&15, row = (lane>>4)*4 + reg  ->  token 16m+4h+r
    #pragma unroll
    for (int m = 0; m < 4; m++)
        #pragma unroll
        for (int nt = 0; nt < 3; nt++)
            #pragma unroll
            for (int r = 0; r < 4; r++)
                sc[w][m * 16 + h * 4 + r][nt * 16 + nl] = acc[m][nt][r];

    __syncthreads();   // cheap; guarantees LDS visibility before scan

    float arr[NC];
    #pragma unroll
    for (int c = 0; c < NC; c++)
        arr[c] = sc[w][lane][c] + biasv[c];   // biasv: wave-uniform s_loads
    pk[t0 + lane] = argmin_pack(arr);
}

// ---------------------------------------------------------------------------
// Kernel B: streaming output (verbatim round-0 structure). proj in LDS; wave
// handles 64 tokens, lane covers 4 consecutive v.
// ---------------------------------------------------------------------------
__global__ __launch_bounds__(512) void vq_out(
    const float* __restrict__ x, const unsigned* __restrict__ pk,
    const float* __restrict__ proj, const float* __restrict__ b2,
    float* __restrict__ out0, float* __restrict__ out1,
    float* __restrict__ out2)
{
    __shared__ v4f pl[NC * 64];  // 47 KB: proj as [code][64 x float4]
    const int tid = threadIdx.x;
    for (int i = tid; i < NC * 64; i += 512)
        pl[i] = ((const v4f*)proj)[i];
    __syncthreads();

    const int lane = tid & 63;
    const int w    = tid >> 6;
    const long tbase = (long)blockIdx.x * 512 + (long)w * 64;
    const unsigned pkme = pk[tbase + lane];
    const v4f b2v = ((const v4f*)b2)[lane];

    #pragma unroll 1
    for (int tok = 0; tok < 64; tok++) {
        const unsigned pkt = (unsigned)__shfl((int)pkme, tok);
        v4f o = b2v;
        #pragma unroll
        for (int g = 0; g < 10; g++) {
            const int cc = CB_OFF_H[g] + (int)((pkt >> (3 * g)) & 7u);
            o += pl[cc * 64 + lane];
        }
        const long t = tbase + tok;
        const v4f xv = ((const v4f*)(x + t * VV))[lane];
        v4f s = (o - xv) + xv;   // match reference rounding for out0
        __builtin_nontemporal_store(s, (v4f*)(out0 + t * VV) + lane);

        const v4f d = xv - o;
        float pr = d.x * d.x + d.y * d.y + d.z * d.z + d.w * d.w;
        #pragma unroll
        for (int off = 32; off > 0; off >>= 1)
            pr += __shfl_xor(pr, off);
        if (lane == 0)  out1[t] = pr;
        if (lane == 32) out2[t] = pr;
    }
}

// ---------------------------------------------------------------------------
extern "C" void kernel_launch(void* const* d_in, const int* in_sizes, int n_in,
                              void* d_out, int out_size, void* d_ws, size_t ws_size,
                              hipStream_t stream) {
    const float* x0 = (const float*)d_in[0];
    const float* W1 = (const float*)d_in[1];
    const float* b1 = (const float*)d_in[2];
    const float* W2 = (const float*)d_in[3];
    const float* b2 = (const float*)d_in[4];
    const float* cb[10];
    for (int i = 0; i < 10; i++) cb[i] = (const float*)d_in[5 + i];

    float* ws = (float*)d_ws;
    unsigned short* bfrag = (unsigned short*)ws;   // 24576 ushorts = 49152 B
    float* biasv = ws + 12288;                     // 47 floats (+pad)
    float* proj  = ws + 12352;                     // 47*256 = 12032 floats
    unsigned* pk = (unsigned*)(ws + 24384);        // 262144 uints, 16B aligned

    float* out0 = (float*)d_out;
    float* out1 = out0 + (long)NN * SS * VV;  // 67108864
    float* out2 = out1 + (long)NN * SS;       // +262144

    vq_pre<<<NC + 1, 256, 0, stream>>>(W1, b1, W2,
        cb[0], cb[1], cb[2], cb[3], cb[4], cb[5], cb[6], cb[7], cb[8], cb[9],
        bfrag, biasv, proj);

    vq_score_mfma<<<(int)(TT / 256), 256, 0, stream>>>(x0, bfrag, biasv, pk);

    vq_out<<<(int)(TT / 512), 512, 0, stream>>>(
        x0, pk, proj, b2, out0, out1, out2);
}

// Round 3
// 550.536 us; speedup vs baseline: 1.4907x; 1.0103x over previous
//
#include <hip/hip_runtime.h>

#define NN 16
#define SS 16384
#define VV 256
#define TT ((long)NN * SS)   // 262144 tokens
#define NC 47                // total codes (padded to 48 for MFMA)

static constexpr int CB_SIZES_H[10] = {3, 5, 5, 5, 5, 3, 7, 8, 3, 3};
static constexpr int CB_OFF_H[10]   = {0, 3, 8, 13, 18, 23, 26, 33, 41, 44};

typedef float v4f    __attribute__((ext_vector_type(4)));
typedef float f32x4  __attribute__((ext_vector_type(4)));
typedef short short8 __attribute__((ext_vector_type(8)));
typedef unsigned uint4e __attribute__((ext_vector_type(4)));

// ---------------------------------------------------------------------------
// Precompute (verified r2). su[k][n] = -2*(W1_g^T e_c)[k] split into bf16
// hi/lo in MFMA B-fragment order; biasv; proj.
// ---------------------------------------------------------------------------
__global__ __launch_bounds__(256) void vq_pre(
    const float* __restrict__ W1, const float* __restrict__ b1,
    const float* __restrict__ W2,
    const float* __restrict__ cb0, const float* __restrict__ cb1,
    const float* __restrict__ cb2, const float* __restrict__ cb3,
    const float* __restrict__ cb4, const float* __restrict__ cb5,
    const float* __restrict__ cb6, const float* __restrict__ cb7,
    const float* __restrict__ cb8, const float* __restrict__ cb9,
    unsigned short* __restrict__ bfrag, float* __restrict__ biasv,
    float* __restrict__ proj)
{
    const int gc = blockIdx.x;           // 0..47 (47 = zero pad column)
    const int v  = threadIdx.x;          // 0..255 = k
    const int ks = v >> 5, kl = v & 31, h = kl >> 3, j = kl & 7;

    if (gc >= NC) {                      // pad column: zeros
        const int idx = (ks * 3 + 2) * 512 + (h * 16 + 15) * 8 + j;
        bfrag[idx] = 0;
        bfrag[12288 + idx] = 0;
        return;
    }

    const float* cbs[10] = {cb0, cb1, cb2, cb3, cb4, cb5, cb6, cb7, cb8, cb9};
    int g = 0;
    #pragma unroll
    for (int gg = 1; gg < 10; gg++) if (gc >= CB_OFF_H[gg]) g = gg;
    const int c = gc - CB_OFF_H[g];
    const float* e = cbs[g] + c * 16;

    float su = 0.f, pj = 0.f;
    #pragma unroll
    for (int i = 0; i < 16; i++)
        su = fmaf(W1[(long)(16 * g + i) * VV + v], e[i], su);
    const float s2 = -2.f * su;

    const unsigned u = __builtin_bit_cast(unsigned, s2);
    const float r = s2 - __builtin_bit_cast(float, u & 0xFFFF0000u);
    unsigned t = __builtin_bit_cast(unsigned, r);
    t += 0x7FFFu + ((t >> 16) & 1u);
    const int idx = (ks * 3 + (gc >> 4)) * 512 + (h * 16 + (gc & 15)) * 8 + j;
    bfrag[idx]         = (unsigned short)(u >> 16);
    bfrag[12288 + idx] = (unsigned short)(t >> 16);

    #pragma unroll
    for (int i = 0; i < 16; i++)
        pj = fmaf(e[i], W2[(long)v * 160 + i * 10 + g], pj);
    proj[gc * VV + v] = pj;

    if (v == 0) {
        float b = 0.f;
        #pragma unroll
        for (int i = 0; i < 16; i++)
            b += e[i] * (e[i] - 2.f * b1[16 * g + i]);
        biasv[gc] = b;
    }
}

// ---------------------------------------------------------------------------
static __device__ __forceinline__ void cvt_hi_lo(
    const float4 f0, const float4 f1, short8& ah, short8& al)
{
    const float f[8] = {f0.x, f0.y, f0.z, f0.w, f1.x, f1.y, f1.z, f1.w};
    uint4e H, L;
    #pragma unroll
    for (int p = 0; p < 4; p++) {
        const unsigned u0 = __builtin_bit_cast(unsigned, f[2 * p]);
        const unsigned u1 = __builtin_bit_cast(unsigned, f[2 * p + 1]);
        H[p] = (u0 >> 16) | (u1 & 0xFFFF0000u);
        const float r0 = f[2 * p]     - __builtin_bit_cast(float, u0 & 0xFFFF0000u);
        const float r1 = f[2 * p + 1] - __builtin_bit_cast(float, u1 & 0xFFFF0000u);
        unsigned t0 = __builtin_bit_cast(unsigned, r0);
        unsigned t1 = __builtin_bit_cast(unsigned, r1);
        t0 += 0x7FFFu + ((t0 >> 16) & 1u);
        t1 += 0x7FFFu + ((t1 >> 16) & 1u);
        L[p] = (t0 >> 16) | (t1 & 0xFFFF0000u);
    }
    ah = __builtin_bit_cast(short8, H);
    al = __builtin_bit_cast(short8, L);
}

static __device__ __forceinline__ unsigned argmin_pack(const float* acc) {
    unsigned p = 0;
    #pragma unroll
    for (int g = 0; g < 10; g++) {
        const int off = CB_OFF_H[g];
        const int k = CB_SIZES_H[g];
        float best = acc[off];
        int bi = 0;
        #pragma unroll
        for (int c = 1; c < 8; c++) {
            if (c < k) {
                const float vv = acc[off + c];
                if (vv < best) { best = vv; bi = c; }  // strict <: np first-min
            }
        }
        p |= (unsigned)bi << (3 * g);
    }
    return p;
}

// ---------------------------------------------------------------------------
// Fused kernel. Block = 256 threads / 256 tokens.
// Phase 1: per ks-step, stage x tile [256 tok][32 k] into LDS via
//   global_load_lds with PRE-SWIZZLED global source (lane loads 16B chunk
//   s^(row&7)); fragment reads apply the same XOR -> bank-even ds_read_b128.
//   score = Ahi*Bhi + Ahi*Blo + Alo*Bhi (split-bf16 MFMA, verified r2).
// Phase 1b: C-frag transpose through LDS scan slab, per-lane argmin -> reg.
// Phase 2: proj into same LDS; stream out0/out1/out2; x re-read is block-
//   local and L2/L3-hot.
// ---------------------------------------------------------------------------
__global__ __launch_bounds__(256, 3) void vq_fused(
    const float* __restrict__ x, const unsigned short* __restrict__ bfrag,
    const float* __restrict__ biasv, const float* __restrict__ proj,
    const float* __restrict__ b2,
    float* __restrict__ out0, float* __restrict__ out1,
    float* __restrict__ out2)
{
    __shared__ __align__(16) char smem[4 * 64 * 49 * 4];   // 50176 B union
    float (*sc)[64][49] = (float (*)[64][49])smem;          // scan slabs
    v4f* pl = (v4f*)smem;                                   // phase2 proj

    const int tid  = threadIdx.x;
    const int w    = tid >> 6;
    const int lane = tid & 63;
    const int h    = lane >> 4;          // A: k-group ; C: row-group
    const int nl   = lane & 15;          // A: row     ; B/C: col
    const long t0  = (long)blockIdx.x * 256;

    // staging lane geometry: wave covers 8 rows x 8 chunks per pass
    const int rw = lane >> 3;            // row within wave's 8-row group
    const int sl = lane & 7;             // LDS 16B slot (linear dest)
    // chunk to fetch = sl ^ rw so LDS slot s holds chunk s^(row&7)
    const int g_lane_off = (w * 8 + rw) * VV + ((sl ^ rw) << 2);  // floats

    f32x4 acc[4][3];
    #pragma unroll
    for (int m = 0; m < 4; m++)
        #pragma unroll
        for (int nt = 0; nt < 3; nt++)
            acc[m][nt] = (f32x4){0.f, 0.f, 0.f, 0.f};

    const unsigned short* bh_ptr = bfrag + lane * 8;
    const unsigned short* bl_ptr = bfrag + 12288 + lane * 8;
    const int swz = nl & 7;              // read-side XOR (= row&7)

    #pragma unroll 1
    for (int ks = 0; ks < 8; ks++) {
        __syncthreads();   // previous ks fragment reads done
        const float* gbase = x + t0 * VV + ks * 32 + g_lane_off;
        #pragma unroll
        for (int p = 0; p < 8; p++) {
            char* ldst = smem + (p * 32 + w * 8) * 128;   // wave-uniform base
            __builtin_amdgcn_global_load_lds(
                (const __attribute__((address_space(1))) unsigned*)(gbase + p * 32 * VV),
                (__attribute__((address_space(3))) unsigned*)ldst,
                16, 0, 0);
        }
        __syncthreads();   // implicit vmcnt(0): staged data visible

        short8 bh[3], bl[3];
        #pragma unroll
        for (int nt = 0; nt < 3; nt++) {
            bh[nt] = *(const short8*)(bh_ptr + (ks * 3 + nt) * 512);
            bl[nt] = *(const short8*)(bl_ptr + (ks * 3 + nt) * 512);
        }
        #pragma unroll
        for (int m = 0; m < 4; m++) {
            const int row = w * 64 + m * 16 + nl;
            const char* rbase = smem + row * 128;
            const float4 f0 = *(const float4*)(rbase + (((2 * h    ) ^ swz) << 4));
            const float4 f1 = *(const float4*)(rbase + (((2 * h + 1) ^ swz) << 4));
            short8 ah, al;
            cvt_hi_lo(f0, f1, ah, al);
            #pragma unroll
            for (int nt = 0; nt < 3; nt++) {
                acc[m][nt] = __builtin_amdgcn_mfma_f32_16x16x32_bf16(ah, bh[nt], acc[m][nt], 0, 0, 0);
                acc[m][nt] = __builtin_amdgcn_mfma_f32_16x16x32_bf16(ah, bl[nt], acc[m][nt], 0, 0, 0);
                acc[m][nt] = __builtin_amdgcn_mfma_f32_16x16x32_bf16(al, bh[nt], acc[m][nt], 0, 0, 0);
            }
        }
    }

    // ---- scan: C layout col=lane&15, row=(lane>>4)*4+reg -> token m*16+4h+r
    __syncthreads();   // all waves done reading stage buffer
    #pragma unroll
    for (int m = 0; m < 4; m++)
        #pragma unroll
        for (int nt = 0; nt < 3; nt++)
            #pragma unroll
            for (int r = 0; r < 4; r++)
                sc[w][m * 16 + h * 4 + r][nt * 16 + nl] = acc[m][nt][r];
    // per-wave slab: within-wave write->read ordered by lgkmcnt, no barrier

    float arr[NC];
    #pragma unroll
    for (int c = 0; c < NC; c++)
        arr[c] = sc[w][lane][c] + biasv[c];   // biasv: wave-uniform s_loads
    const unsigned p = argmin_pack(arr);      // token t0 + w*64 + lane

    // ---- phase 2: proj into LDS, stream outputs ----
    __syncthreads();                          // all scan reads done
    for (int i = tid; i < NC * 64; i += 256)
        pl[i] = ((const v4f*)proj)[i];
    __syncthreads();

    const v4f b2v = ((const v4f*)b2)[lane];
    const long tbase = t0 + (long)w * 64;

    #pragma unroll 1
    for (int tok = 0; tok < 64; tok++) {
        const unsigned pkt = (unsigned)__shfl((int)p, tok);
        v4f o = b2v;
        #pragma unroll
        for (int g = 0; g < 10; g++) {
            const int cc = CB_OFF_H[g] + (int)((pkt >> (3 * g)) & 7u);
            o += pl[cc * 64 + lane];
        }
        const long t = tbase + tok;
        const v4f xv = ((const v4f*)(x + t * VV))[lane];   // L2/L3-hot re-read
        v4f s = (o - xv) + xv;   // match reference rounding for out0
        __builtin_nontemporal_store(s, (v4f*)(out0 + t * VV) + lane);

        const v4f d = xv - o;
        float pr = d.x * d.x + d.y * d.y + d.z * d.z + d.w * d.w;
        #pragma unroll
        for (int off = 32; off > 0; off >>= 1)
            pr += __shfl_xor(pr, off);
        if (lane == 0)  out1[t] = pr;
        if (lane == 32) out2[t] = pr;
    }
}

// ---------------------------------------------------------------------------
extern "C" void kernel_launch(void* const* d_in, const int* in_sizes, int n_in,
                              void* d_out, int out_size, void* d_ws, size_t ws_size,
                              hipStream_t stream) {
    const float* x0 = (const float*)d_in[0];
    const float* W1 = (const float*)d_in[1];
    const float* b1 = (const float*)d_in[2];
    const float* W2 = (const float*)d_in[3];
    const float* b2 = (const float*)d_in[4];
    const float* cb[10];
    for (int i = 0; i < 10; i++) cb[i] = (const float*)d_in[5 + i];

    float* ws = (float*)d_ws;
    unsigned short* bfrag = (unsigned short*)ws;   // 24576 ushorts = 49152 B
    float* biasv = ws + 12288;                     // 47 floats (+pad)
    float* proj  = ws + 12352;                     // 47*256 = 12032 floats

    float* out0 = (float*)d_out;
    float* out1 = out0 + (long)NN * SS * VV;  // 67108864
    float* out2 = out1 + (long)NN * SS;       // +262144

    vq_pre<<<NC + 1, 256, 0, stream>>>(W1, b1, W2,
        cb[0], cb[1], cb[2], cb[3], cb[4], cb[5], cb[6], cb[7], cb[8], cb[9],
        bfrag, biasv, proj);

    vq_fused<<<(int)(TT / 256), 256, 0, stream>>>(
        x0, bfrag, biasv, proj, b2, out0, out1, out2);
}